// Round 16
// baseline (1667.543 us; speedup 1.0000x reference)
//
#include <hip/hip_runtime.h>

#define SEQ 4096
#define BATCH 512
#define INP 8
#define HID 30
#define LOG2E 1.44269504088896340736f

typedef float f32x2 __attribute__((ext_vector_type(2)));
typedef float f32x4 __attribute__((ext_vector_type(4)));
typedef unsigned uint2v __attribute__((ext_vector_type(2)));

#define RCP(v)  __builtin_amdgcn_rcpf(v)
#if __has_builtin(__builtin_amdgcn_exp2f)
#define EXP2(v) __builtin_amdgcn_exp2f(v)
#else
#define EXP2(v) exp2f(v)
#endif
#define PKFMA(a, b, c) __builtin_elementwise_fma(a, b, c)

__device__ __forceinline__ f32x2 mk2(float a, float b) {
    f32x2 r; r.x = a; r.y = b; return r;
}

// permlane32_swap with both operands = v:
//   returns {lo_rep = [v_lo32 | v_lo32], hi_rep = [v_hi32 | v_hi32]}
__device__ __forceinline__ void rep_halves(float v, float& lo_rep, float& hi_rep) {
#if __has_builtin(__builtin_amdgcn_permlane32_swap)
    uint2v r = __builtin_amdgcn_permlane32_swap(
        __float_as_uint(v), __float_as_uint(v), false, false);
    lo_rep = __uint_as_float(r.x);
    hi_rep = __uint_as_float(r.y);
#else
    float other = __shfl_xor(v, 32, 64);
    bool hi = (threadIdx.x & 32) != 0;
    lo_rep = hi ? other : v;
    hi_rep = hi ? v : other;
#endif
}

template <int CTRL>
__device__ __forceinline__ float dpp_sum_step(float v) {
    return v + __uint_as_float(__builtin_amdgcn_update_dpp(
        0, (int)__float_as_uint(v), CTRL, 0xf, 0xf, true));
}

// Sum within each 32-lane group, pure VALU. Total valid in lanes 15,31,47,63.
__device__ __forceinline__ float group32_reduce(float v) {
    v = dpp_sum_step<0x111>(v);  // row_shr:1
    v = dpp_sum_step<0x112>(v);  // row_shr:2
    v = dpp_sum_step<0x114>(v);  // row_shr:4
    v = dpp_sum_step<0x118>(v);  // row_shr:8
#if __has_builtin(__builtin_amdgcn_permlane16_swap)
    uint2v r = __builtin_amdgcn_permlane16_swap(
        __float_as_uint(v), __float_as_uint(v), false, false);
    return __uint_as_float(r.x) + __uint_as_float(r.y);
#else
    return v + __shfl_xor(v, 16, 64);
#endif
}

// One wave = TWO chains (P,Q), statement-interleaved so the two independent
// serial dependency chains (trans-op + FMA latency) overlap in the in-order
// stream. Loop is VMEM-free (x staged through double-buffered LDS chunks).
// Shared weights; per-chain hrf2/c2/pre/x-slots. One LDS h-broadcast window
// serves both chains: P at s_h[0..63] (reads s_h4[0..7]), Q at s_h[64..127]
// (reads s_h4[16..23] -- R15 bug was reading s_h4[8..15] = P's upper half).
__global__ __launch_bounds__(64)
__attribute__((amdgpu_waves_per_eu(1, 1)))
void lstm_chain_kernel(
    const float* __restrict__ x,     // [SEQ,BATCH,INP]
    const float* __restrict__ W_ih,  // [4H, INP]
    const float* __restrict__ W_hh,  // [4H, HID]
    const float* __restrict__ b_ih,  // [4H]
    const float* __restrict__ b_hh,  // [4H]
    const float* __restrict__ W_lin, // [1, HID]
    const float* __restrict__ b_lin, // [1]
    float* __restrict__ out)         // [SEQ,BATCH,1]
{
    const int lane = threadIdx.x;
    // XCD-aware swizzle on chain PAIRS: consecutive pairs share x-lines /
    // out-sectors within one XCD's L2.
    const int g    = blockIdx.x;                    // [0,256)
    const int b0   = 2 * ((g & 7) * 32 + (g >> 3)); // chains b0, b0+1
    const int j    = lane & 31;
    const int half = lane >> 5;
    const int jc   = j < HID ? j : HID - 1;
    const int ra   = half * HID + jc;            // i (half0) / f (half1): sigmoid
    const int rb   = 2 * HID + half * HID + jc;  // g (half0, tanh) / o (half1, sigmoid)

    const float sA   = -LOG2E;
    const float sB   = half ? -LOG2E : 2.0f * LOG2E;
    const float T2L  = 2.0f * LOG2E;
    const float IT2L = 1.0f / (2.0f * LOG2E);
    const float sclB2 = half ? T2L : -2.0f * T2L;
    const float addB2 = half ? 0.0f : T2L;

    // ---- shared packed weights, pre-scaled, pinned in VGPR pairs ----
    f32x2 wih2_a[INP / 2], wih2_b[INP / 2];
#pragma unroll
    for (int i = 0; i < INP / 2; ++i) {
        f32x2 wa = mk2(W_ih[ra * INP + 2 * i] * sA, W_ih[ra * INP + 2 * i + 1] * sA);
        f32x2 wb = mk2(W_ih[rb * INP + 2 * i] * sB, W_ih[rb * INP + 2 * i + 1] * sB);
        asm volatile("" : "+v"(wa));
        asm volatile("" : "+v"(wb));
        wih2_a[i] = wa;
        wih2_b[i] = wb;
    }
    f32x2 whh2_a[HID / 2], whh2_b[HID / 2];
#pragma unroll
    for (int k = 0; k < HID / 2; ++k) {
        f32x2 wa = mk2(W_hh[ra * HID + 2 * k] * sA, W_hh[ra * HID + 2 * k + 1] * sA);
        f32x2 wb = mk2(W_hh[rb * HID + 2 * k] * sB, W_hh[rb * HID + 2 * k + 1] * sB);
        asm volatile("" : "+v"(wa));
        asm volatile("" : "+v"(wb));
        whh2_a[k] = wa;
        whh2_b[k] = wb;
    }
    const float bias_sa = (b_ih[ra] + b_hh[ra]) * sA;
    const float bias_sb = (b_ih[rb] + b_hh[rb]) * sB;
    const float blin    = b_lin[0];
    const float wlin    = (j < HID) ? W_lin[j] : 0.0f;

    __shared__ float s_y[2 * SEQ];                      // P then Q
    __shared__ __align__(16) float s_h[128];            // P: 0..63, Q: 64..127
    __shared__ __align__(16) float s_x[2 * 2 * 64 * INP]; // [buf][chain][step][inp]

    f32x4* sx4 = reinterpret_cast<f32x4*>(s_x);
    const f32x4* sx4c = reinterpret_cast<const f32x4*>(s_x);
    const f32x4* s_h4 = reinterpret_cast<const f32x4*>(s_h);

    f32x2 hrf2P[HID / 2], hrf2Q[HID / 2];
#pragma unroll
    for (int k = 0; k < HID / 2; ++k) { hrf2P[k] = mk2(0.0f, 0.0f); hrf2Q[k] = mk2(0.0f, 0.0f); }
    float c2P = 0.0f, c2Q = 0.0f;

    // ---- chunked x staging for both chains ----
    f32x4 stg0, stg1, stg2, stg3;

#define STAGELOAD(CH2) do {                                                   \
    int _s0 = (CH2) * 64 + (lane >> 1);                                       \
    int _s1 = _s0 + 32;                                                       \
    if (_s0 > SEQ - 1) _s0 = SEQ - 1;                                         \
    if (_s1 > SEQ - 1) _s1 = SEQ - 1;                                         \
    const f32x4* _pP0 = (const f32x4*)(x + ((size_t)_s0 * BATCH + b0) * INP) + (lane & 1);     \
    const f32x4* _pP1 = (const f32x4*)(x + ((size_t)_s1 * BATCH + b0) * INP) + (lane & 1);     \
    const f32x4* _pQ0 = (const f32x4*)(x + ((size_t)_s0 * BATCH + b0 + 1) * INP) + (lane & 1); \
    const f32x4* _pQ1 = (const f32x4*)(x + ((size_t)_s1 * BATCH + b0 + 1) * INP) + (lane & 1); \
    stg0 = *_pP0;  stg1 = *_pP1;  stg2 = *_pQ0;  stg3 = *_pQ1;                \
} while (0)

#define STAGEWRITE(CHW) do {                                                  \
    f32x4* _d = sx4 + ((CHW) & 1) * 256;                                      \
    _d[lane]       = stg0;                                                    \
    _d[64 + lane]  = stg1;                                                    \
    _d[128 + lane] = stg2;                                                    \
    _d[192 + lane] = stg3;                                                    \
} while (0)

#define LOADXL2(XAP, XBP, XAQ, XBQ, TL) do {                                  \
    int _e = (((TL) >> 6) & 1) * 256 + ((TL) & 63) * 2;                       \
    XAP = sx4c[_e];        XBP = sx4c[_e + 1];                                \
    XAQ = sx4c[128 + _e];  XBQ = sx4c[128 + _e + 1];                          \
} while (0)

    // rolling pre-activations for NEXT step, per chain
    f32x2 preA0P, preA1P, preB0P, preB1P;
    f32x2 preA0Q, preA1Q, preB0Q, preB1Q;

#define IHPRE2(XAP, XBP, XAQ, XBQ) do {                                       \
    f32x2 p01 = __builtin_shufflevector(XAP, XAP, 0, 1);                      \
    f32x2 q01 = __builtin_shufflevector(XAQ, XAQ, 0, 1);                      \
    f32x2 p23 = __builtin_shufflevector(XAP, XAP, 2, 3);                      \
    f32x2 q23 = __builtin_shufflevector(XAQ, XAQ, 2, 3);                      \
    f32x2 p45 = __builtin_shufflevector(XBP, XBP, 0, 1);                      \
    f32x2 q45 = __builtin_shufflevector(XBQ, XBQ, 0, 1);                      \
    f32x2 p67 = __builtin_shufflevector(XBP, XBP, 2, 3);                      \
    f32x2 q67 = __builtin_shufflevector(XBQ, XBQ, 2, 3);                      \
    preA0P = PKFMA(p01, wih2_a[0], mk2(bias_sa, 0.0f));                       \
    preA0Q = PKFMA(q01, wih2_a[0], mk2(bias_sa, 0.0f));                       \
    preB0P = PKFMA(p01, wih2_b[0], mk2(bias_sb, 0.0f));                       \
    preB0Q = PKFMA(q01, wih2_b[0], mk2(bias_sb, 0.0f));                       \
    preA1P = PKFMA(p23, wih2_a[1], mk2(0.0f, 0.0f));                          \
    preA1Q = PKFMA(q23, wih2_a[1], mk2(0.0f, 0.0f));                          \
    preB1P = PKFMA(p23, wih2_b[1], mk2(0.0f, 0.0f));                          \
    preB1Q = PKFMA(q23, wih2_b[1], mk2(0.0f, 0.0f));                          \
    preA0P = PKFMA(p45, wih2_a[2], preA0P);                                   \
    preA0Q = PKFMA(q45, wih2_a[2], preA0Q);                                   \
    preB0P = PKFMA(p45, wih2_b[2], preB0P);                                   \
    preB0Q = PKFMA(q45, wih2_b[2], preB0Q);                                   \
    preA1P = PKFMA(p67, wih2_a[3], preA1P);                                   \
    preA1Q = PKFMA(q67, wih2_a[3], preA1Q);                                   \
    preB1P = PKFMA(p67, wih2_b[3], preB1P);                                   \
    preB1Q = PKFMA(q67, wih2_b[3], preB1Q);                                   \
} while (0)

    // prologue
    STAGELOAD(0);
    STAGEWRITE(0);
    STAGELOAD(1);

    f32x4 x0AP, x0BP, x0AQ, x0BQ;   // slot 0
    f32x4 x1AP, x1BP, x1AQ, x1BQ;   // slot 1
    LOADXL2(x0AP, x0BP, x0AQ, x0BQ, 0);
    LOADXL2(x1AP, x1BP, x1AQ, x1BQ, 1);
    IHPRE2(x0AP, x0BP, x0AQ, x0BQ);  // pre for t=0

// STEP2(T, nX*: slot holding x[T+1] (feeds rolling pre),
//          lX*: slot to reload with x[TL=T+2])
#define STEP2(T, nAP, nBP, nAQ, nBQ, lAP, lBP, lAQ, lBQ, TL) do {             \
    f32x2 pA0 = preA0P, pA1 = preA1P, pB0 = preB0P, pB1 = preB1P;             \
    f32x2 qA0 = preA0Q, qA1 = preA1Q, qB0 = preB0Q, qB1 = preB1Q;             \
    _Pragma("unroll")                                                         \
    for (int k = 0; k < HID / 2 - 1; k += 2) {                                \
        pA0 = PKFMA(hrf2P[k],   whh2_a[k],   pA0);                            \
        qA0 = PKFMA(hrf2Q[k],   whh2_a[k],   qA0);                            \
        pB0 = PKFMA(hrf2P[k],   whh2_b[k],   pB0);                            \
        qB0 = PKFMA(hrf2Q[k],   whh2_b[k],   qB0);                            \
        pA1 = PKFMA(hrf2P[k+1], whh2_a[k+1], pA1);                            \
        qA1 = PKFMA(hrf2Q[k+1], whh2_a[k+1], qA1);                            \
        pB1 = PKFMA(hrf2P[k+1], whh2_b[k+1], pB1);                            \
        qB1 = PKFMA(hrf2Q[k+1], whh2_b[k+1], qB1);                            \
    }                                                                         \
    pA0 = PKFMA(hrf2P[HID/2-1], whh2_a[HID/2-1], pA0);                        \
    qA0 = PKFMA(hrf2Q[HID/2-1], whh2_a[HID/2-1], qA0);                        \
    pB0 = PKFMA(hrf2P[HID/2-1], whh2_b[HID/2-1], pB0);                        \
    qB0 = PKFMA(hrf2Q[HID/2-1], whh2_b[HID/2-1], qB0);                        \
    f32x2 AsP = pA0 + pA1;  f32x2 AsQ = qA0 + qA1;                            \
    f32x2 BsP = pB0 + pB1;  f32x2 BsQ = qB0 + qB1;                            \
    float uaP = AsP.x + AsP.y;  float uaQ = AsQ.x + AsQ.y;                    \
    float ubP = BsP.x + BsP.y;  float ubQ = BsQ.x + BsQ.y;                    \
    float AvP  = RCP(1.0f + EXP2(uaP));                                       \
    float AvQ  = RCP(1.0f + EXP2(uaQ));                                       \
    float sBvP = RCP(1.0f + EXP2(ubP));                                       \
    float sBvQ = RCP(1.0f + EXP2(ubQ));                                       \
    float BvP2 = fmaf(sBvP, sclB2, addB2);                                    \
    float BvQ2 = fmaf(sBvQ, sclB2, addB2);                                    \
    /* one-product swap: m = i*g2 (half0) | f*c2_prev (half1) */              \
    float mP = AvP * (half ? c2P : BvP2);                                     \
    float mQ = AvQ * (half ? c2Q : BvQ2);                                     \
    float mloP, mhiP, mloQ, mhiQ;                                             \
    rep_halves(mP, mloP, mhiP);                                               \
    rep_halves(mQ, mloQ, mhiQ);                                               \
    c2P = mloP + mhiP;                                                        \
    c2Q = mloQ + mhiQ;                                                        \
    float gloP, oT2P, gloQ, oT2Q;                                             \
    rep_halves(BvP2, gloP, oT2P);                                             \
    rep_halves(BvQ2, gloQ, oT2Q);                                             \
    float oo_uP = oT2P * IT2L;           float oo_uQ = oT2Q * IT2L;           \
    float n2oP  = oT2P * (-2.0f * IT2L); float n2oQ  = oT2Q * (-2.0f * IT2L); \
    float scP = RCP(1.0f + EXP2(c2P));                                        \
    float scQ = RCP(1.0f + EXP2(c2Q));                                        \
    float hP  = fmaf(scP, n2oP, oo_uP);                                       \
    float hQ  = fmaf(scQ, n2oQ, oo_uQ);                                       \
    s_h[lane]      = hP;                                                      \
    s_h[64 + lane] = hQ;                                                      \
    f32x4 hvP0 = s_h4[0],  hvP1 = s_h4[1],  hvP2 = s_h4[2],  hvP3 = s_h4[3];  \
    f32x4 hvP4 = s_h4[4],  hvP5 = s_h4[5],  hvP6 = s_h4[6],  hvP7 = s_h4[7];  \
    f32x4 hvQ0 = s_h4[16], hvQ1 = s_h4[17], hvQ2 = s_h4[18], hvQ3 = s_h4[19]; \
    f32x4 hvQ4 = s_h4[20], hvQ5 = s_h4[21], hvQ6 = s_h4[22], hvQ7 = s_h4[23]; \
    /* ---- read shadow: independent work ---- */                             \
    float pP = group32_reduce(hP * wlin);                                     \
    float pQ = group32_reduce(hQ * wlin);                                     \
    if (lane == 31) { s_y[T] = pP + blin;  s_y[SEQ + (T)] = pQ + blin; }      \
    LOADXL2(lAP, lBP, lAQ, lBQ, TL);                                          \
    IHPRE2(nAP, nBP, nAQ, nBQ);                                               \
    /* ---- unpack broadcasts ---- */                                         \
    hrf2P[0]  = __builtin_shufflevector(hvP0, hvP0, 0, 1);                    \
    hrf2P[1]  = __builtin_shufflevector(hvP0, hvP0, 2, 3);                    \
    hrf2P[2]  = __builtin_shufflevector(hvP1, hvP1, 0, 1);                    \
    hrf2P[3]  = __builtin_shufflevector(hvP1, hvP1, 2, 3);                    \
    hrf2P[4]  = __builtin_shufflevector(hvP2, hvP2, 0, 1);                    \
    hrf2P[5]  = __builtin_shufflevector(hvP2, hvP2, 2, 3);                    \
    hrf2P[6]  = __builtin_shufflevector(hvP3, hvP3, 0, 1);                    \
    hrf2P[7]  = __builtin_shufflevector(hvP3, hvP3, 2, 3);                    \
    hrf2P[8]  = __builtin_shufflevector(hvP4, hvP4, 0, 1);                    \
    hrf2P[9]  = __builtin_shufflevector(hvP4, hvP4, 2, 3);                    \
    hrf2P[10] = __builtin_shufflevector(hvP5, hvP5, 0, 1);                    \
    hrf2P[11] = __builtin_shufflevector(hvP5, hvP5, 2, 3);                    \
    hrf2P[12] = __builtin_shufflevector(hvP6, hvP6, 0, 1);                    \
    hrf2P[13] = __builtin_shufflevector(hvP6, hvP6, 2, 3);                    \
    hrf2P[14] = __builtin_shufflevector(hvP7, hvP7, 0, 1);                    \
    hrf2Q[0]  = __builtin_shufflevector(hvQ0, hvQ0, 0, 1);                    \
    hrf2Q[1]  = __builtin_shufflevector(hvQ0, hvQ0, 2, 3);                    \
    hrf2Q[2]  = __builtin_shufflevector(hvQ1, hvQ1, 0, 1);                    \
    hrf2Q[3]  = __builtin_shufflevector(hvQ1, hvQ1, 2, 3);                    \
    hrf2Q[4]  = __builtin_shufflevector(hvQ2, hvQ2, 0, 1);                    \
    hrf2Q[5]  = __builtin_shufflevector(hvQ2, hvQ2, 2, 3);                    \
    hrf2Q[6]  = __builtin_shufflevector(hvQ3, hvQ3, 0, 1);                    \
    hrf2Q[7]  = __builtin_shufflevector(hvQ3, hvQ3, 2, 3);                    \
    hrf2Q[8]  = __builtin_shufflevector(hvQ4, hvQ4, 0, 1);                    \
    hrf2Q[9]  = __builtin_shufflevector(hvQ4, hvQ4, 2, 3);                    \
    hrf2Q[10] = __builtin_shufflevector(hvQ5, hvQ5, 0, 1);                    \
    hrf2Q[11] = __builtin_shufflevector(hvQ5, hvQ5, 2, 3);                    \
    hrf2Q[12] = __builtin_shufflevector(hvQ6, hvQ6, 0, 1);                    \
    hrf2Q[13] = __builtin_shufflevector(hvQ6, hvQ6, 2, 3);                    \
    hrf2Q[14] = __builtin_shufflevector(hvQ7, hvQ7, 0, 1);                    \
} while (0)

    for (int ch = 0; ch < SEQ / 64; ++ch) {
        STAGEWRITE(ch + 1);
        STAGELOAD(ch + 2);
        const int t0 = ch * 64;
#pragma unroll 1
        for (int tt = 0; tt < 64; tt += 2) {
            const int t = t0 + tt;
            STEP2(t,     x1AP, x1BP, x1AQ, x1BQ, x0AP, x0BP, x0AQ, x0BQ, t + 2);
            STEP2(t + 1, x0AP, x0BP, x0AQ, x0BQ, x1AP, x1BP, x1AQ, x1BQ, t + 3);
        }
    }
#undef STEP2
#undef IHPRE2
#undef LOADXL2
#undef STAGELOAD
#undef STAGEWRITE

    // ---- dump y for both chains ----
    __syncthreads();  // single wave; orders the last ds_write before reads
    const float4* s_y4 = reinterpret_cast<const float4*>(s_y);
#pragma unroll 2
    for (int c = 0; c < 2; ++c) {
#pragma unroll 4
        for (int it = 0; it < SEQ / 256; ++it) {
            int tbase = it * 256 + lane * 4;
            float4 v = s_y4[(c * SEQ + tbase) >> 2];
            out[(size_t)(tbase + 0) * BATCH + b0 + c] = v.x;
            out[(size_t)(tbase + 1) * BATCH + b0 + c] = v.y;
            out[(size_t)(tbase + 2) * BATCH + b0 + c] = v.z;
            out[(size_t)(tbase + 3) * BATCH + b0 + c] = v.w;
        }
    }
}

extern "C" void kernel_launch(void* const* d_in, const int* in_sizes, int n_in,
                              void* d_out, int out_size, void* d_ws, size_t ws_size,
                              hipStream_t stream) {
    const float* x     = (const float*)d_in[0];
    const float* W_ih  = (const float*)d_in[1];
    const float* W_hh  = (const float*)d_in[2];
    const float* b_ih  = (const float*)d_in[3];
    const float* b_hh  = (const float*)d_in[4];
    const float* W_lin = (const float*)d_in[5];
    const float* b_lin = (const float*)d_in[6];
    float* out = (float*)d_out;

    lstm_chain_kernel<<<dim3(BATCH / 2), dim3(64), 0, stream>>>(
        x, W_ih, W_hh, b_ih, b_hh, W_lin, b_lin, out);
}

// Round 17
// 1385.318 us; speedup vs baseline: 1.2037x; 1.2037x over previous
//
#include <hip/hip_runtime.h>

#define SEQ 4096
#define BATCH 512
#define INP 8
#define HID 30
#define LOG2E 1.44269504088896340736f

typedef float f32x2 __attribute__((ext_vector_type(2)));
typedef float f32x4 __attribute__((ext_vector_type(4)));
typedef unsigned uint2v __attribute__((ext_vector_type(2)));

#define RCP(v)  __builtin_amdgcn_rcpf(v)
#if __has_builtin(__builtin_amdgcn_exp2f)
#define EXP2(v) __builtin_amdgcn_exp2f(v)
#else
#define EXP2(v) exp2f(v)
#endif
#define PKFMA(a, b, c) __builtin_elementwise_fma(a, b, c)

__device__ __forceinline__ f32x2 mk2(float a, float b) {
    f32x2 r; r.x = a; r.y = b; return r;
}

template <int CTRL>
__device__ __forceinline__ float dpp_sum_step(float v) {
    return v + __uint_as_float(__builtin_amdgcn_update_dpp(
        0, (int)__float_as_uint(v), CTRL, 0xf, 0xf, true));
}

// Sum within each 32-lane group, pure VALU. Group total valid in lanes
// 15,31 (group 0) and 47,63 (group 1).
__device__ __forceinline__ float group32_reduce(float v) {
    v = dpp_sum_step<0x111>(v);  // row_shr:1
    v = dpp_sum_step<0x112>(v);  // row_shr:2
    v = dpp_sum_step<0x114>(v);  // row_shr:4
    v = dpp_sum_step<0x118>(v);  // row_shr:8
#if __has_builtin(__builtin_amdgcn_permlane16_swap)
    uint2v r = __builtin_amdgcn_permlane16_swap(
        __float_as_uint(v), __float_as_uint(v), false, false);
    return __uint_as_float(r.x) + __uint_as_float(r.y);
#else
    return v + __shfl_xor(v, 16, 64);
#endif
}

// One wave = TWO chains IN SIMD: lanes 0-31 = chain P, lanes 32-63 = chain Q.
// Lane j of each 32-group owns hidden unit j with ALL FOUR gate rows
// (i,f,g,o = 4 x dot-30) -> the LSTM cell update is entirely lane-local
// (no permlane swaps on the serial chain). One instruction stream advances
// both chains simultaneously; per-chain issue is halved vs one-chain/wave.
// Loop is VMEM-free (x staged through double-buffered LDS chunks, R16
// layout). h broadcast via LDS round trip per 32-group (write 30, read
// 8x b128), shadowed by the y-reduce + next staging.
__global__ __launch_bounds__(64)
__attribute__((amdgpu_waves_per_eu(1, 1)))
void lstm_chain_kernel(
    const float* __restrict__ x,     // [SEQ,BATCH,INP]
    const float* __restrict__ W_ih,  // [4H, INP]
    const float* __restrict__ W_hh,  // [4H, HID]
    const float* __restrict__ b_ih,  // [4H]
    const float* __restrict__ b_hh,  // [4H]
    const float* __restrict__ W_lin, // [1, HID]
    const float* __restrict__ b_lin, // [1]
    float* __restrict__ out)         // [SEQ,BATCH,1]
{
    const int lane  = threadIdx.x;
    // XCD-aware swizzle on chain pairs
    const int g     = blockIdx.x;                    // [0,256)
    const int b0    = 2 * ((g & 7) * 32 + (g >> 3)); // chains b0, b0+1
    const int chain = lane >> 5;
    const int j     = lane & 31;
    const int jc    = j < HID ? j : HID - 1;
    const int ri    = jc;            // i row (sigmoid)
    const int rf    = HID + jc;      // f row (sigmoid)
    const int rg    = 2 * HID + jc;  // g row (tanh)
    const int ro    = 3 * HID + jc;  // o row (sigmoid)

    const float sS  = -LOG2E;        // sigmoid fold: sig(v)=rcp(1+exp2(-L2E*v))
    const float sG  = 2.0f * LOG2E;  // tanh fold: tanh(v)=1-2*rcp(1+exp2(2*L2E*v))
    const float T2L = 2.0f * LOG2E;  // tanh(c) via exp2(c*T2L); carry c2=c*T2L

    // ---- per-lane weights (shared across chains), pre-scaled, pinned ----
    f32x2 whh_i[HID / 2], whh_f[HID / 2], whh_g[HID / 2], whh_o[HID / 2];
#pragma unroll
    for (int k = 0; k < HID / 2; ++k) {
        f32x2 wi = mk2(W_hh[ri * HID + 2 * k] * sS, W_hh[ri * HID + 2 * k + 1] * sS);
        f32x2 wf = mk2(W_hh[rf * HID + 2 * k] * sS, W_hh[rf * HID + 2 * k + 1] * sS);
        f32x2 wg = mk2(W_hh[rg * HID + 2 * k] * sG, W_hh[rg * HID + 2 * k + 1] * sG);
        f32x2 wo = mk2(W_hh[ro * HID + 2 * k] * sS, W_hh[ro * HID + 2 * k + 1] * sS);
        asm volatile("" : "+v"(wi));
        asm volatile("" : "+v"(wf));
        asm volatile("" : "+v"(wg));
        asm volatile("" : "+v"(wo));
        whh_i[k] = wi;  whh_f[k] = wf;  whh_g[k] = wg;  whh_o[k] = wo;
    }
    f32x2 wih_i[INP / 2], wih_f[INP / 2], wih_g[INP / 2], wih_o[INP / 2];
#pragma unroll
    for (int k = 0; k < INP / 2; ++k) {
        f32x2 wi = mk2(W_ih[ri * INP + 2 * k] * sS, W_ih[ri * INP + 2 * k + 1] * sS);
        f32x2 wf = mk2(W_ih[rf * INP + 2 * k] * sS, W_ih[rf * INP + 2 * k + 1] * sS);
        f32x2 wg = mk2(W_ih[rg * INP + 2 * k] * sG, W_ih[rg * INP + 2 * k + 1] * sG);
        f32x2 wo = mk2(W_ih[ro * INP + 2 * k] * sS, W_ih[ro * INP + 2 * k + 1] * sS);
        asm volatile("" : "+v"(wi));
        asm volatile("" : "+v"(wf));
        asm volatile("" : "+v"(wg));
        asm volatile("" : "+v"(wo));
        wih_i[k] = wi;  wih_f[k] = wf;  wih_g[k] = wg;  wih_o[k] = wo;
    }
    const float bi = (b_ih[ri] + b_hh[ri]) * sS;
    const float bf = (b_ih[rf] + b_hh[rf]) * sS;
    const float bg = (b_ih[rg] + b_hh[rg]) * sG;
    const float bo = (b_ih[ro] + b_hh[ro]) * sS;
    const float blin = b_lin[0];
    const float wlin = (j < HID) ? W_lin[j] : 0.0f;

    __shared__ float s_y[2 * SEQ];                        // P then Q
    __shared__ __align__(16) float s_h[64];               // P: 0..31, Q: 32..63
    __shared__ __align__(16) float s_x[2 * 2 * 64 * INP]; // [buf][chain][step][inp]

    f32x4* sx4 = reinterpret_cast<f32x4*>(s_x);
    const f32x4* sx4c = reinterpret_cast<const f32x4*>(s_x);
    const f32x4* s_h4 = reinterpret_cast<const f32x4*>(s_h);

    f32x2 hrf2[HID / 2];
#pragma unroll
    for (int k = 0; k < HID / 2; ++k) hrf2[k] = mk2(0.0f, 0.0f);
    float c2 = 0.0f;  // carried state: c * T2L

    // ---- chunked x staging for both chains (R16 layout) ----
    f32x4 stg0, stg1, stg2, stg3;

#define STAGELOAD(CH2) do {                                                   \
    int _s0 = (CH2) * 64 + (lane >> 1);                                       \
    int _s1 = _s0 + 32;                                                       \
    if (_s0 > SEQ - 1) _s0 = SEQ - 1;                                         \
    if (_s1 > SEQ - 1) _s1 = SEQ - 1;                                         \
    const f32x4* _pP0 = (const f32x4*)(x + ((size_t)_s0 * BATCH + b0) * INP) + (lane & 1);     \
    const f32x4* _pP1 = (const f32x4*)(x + ((size_t)_s1 * BATCH + b0) * INP) + (lane & 1);     \
    const f32x4* _pQ0 = (const f32x4*)(x + ((size_t)_s0 * BATCH + b0 + 1) * INP) + (lane & 1); \
    const f32x4* _pQ1 = (const f32x4*)(x + ((size_t)_s1 * BATCH + b0 + 1) * INP) + (lane & 1); \
    stg0 = *_pP0;  stg1 = *_pP1;  stg2 = *_pQ0;  stg3 = *_pQ1;                \
} while (0)

#define STAGEWRITE(CHW) do {                                                  \
    f32x4* _d = sx4 + ((CHW) & 1) * 256;                                      \
    _d[lane]       = stg0;                                                    \
    _d[64 + lane]  = stg1;                                                    \
    _d[128 + lane] = stg2;                                                    \
    _d[192 + lane] = stg3;                                                    \
} while (0)

    // prologue
    STAGELOAD(0);
    STAGEWRITE(0);
    STAGELOAD(1);

#define STEP(T) do {                                                          \
    /* x for this step (written >=1 chunk ago; lgkm only) */                  \
    int _xe = (((T) >> 6) & 1) * 256 + chain * 128 + ((T) & 63) * 2;          \
    f32x4 xa = sx4c[_xe];                                                     \
    f32x4 xb = sx4c[_xe + 1];                                                 \
    f32x2 ai0 = mk2(bi, 0.0f), ai1 = mk2(0.0f, 0.0f);                         \
    f32x2 af0 = mk2(bf, 0.0f), af1 = mk2(0.0f, 0.0f);                         \
    f32x2 ag0 = mk2(bg, 0.0f), ag1 = mk2(0.0f, 0.0f);                         \
    f32x2 ao0 = mk2(bo, 0.0f), ao1 = mk2(0.0f, 0.0f);                         \
    _Pragma("unroll")                                                         \
    for (int k = 0; k < HID / 2 - 1; k += 2) {                                \
        ai0 = PKFMA(hrf2[k],   whh_i[k],   ai0);                              \
        af0 = PKFMA(hrf2[k],   whh_f[k],   af0);                              \
        ag0 = PKFMA(hrf2[k],   whh_g[k],   ag0);                              \
        ao0 = PKFMA(hrf2[k],   whh_o[k],   ao0);                              \
        ai1 = PKFMA(hrf2[k+1], whh_i[k+1], ai1);                              \
        af1 = PKFMA(hrf2[k+1], whh_f[k+1], af1);                              \
        ag1 = PKFMA(hrf2[k+1], whh_g[k+1], ag1);                              \
        ao1 = PKFMA(hrf2[k+1], whh_o[k+1], ao1);                              \
    }                                                                         \
    ai0 = PKFMA(hrf2[HID/2-1], whh_i[HID/2-1], ai0);                          \
    af0 = PKFMA(hrf2[HID/2-1], whh_f[HID/2-1], af0);                          \
    ag0 = PKFMA(hrf2[HID/2-1], whh_g[HID/2-1], ag0);                          \
    ao0 = PKFMA(hrf2[HID/2-1], whh_o[HID/2-1], ao0);                          \
    f32x2 x01 = __builtin_shufflevector(xa, xa, 0, 1);                        \
    f32x2 x23 = __builtin_shufflevector(xa, xa, 2, 3);                        \
    f32x2 x45 = __builtin_shufflevector(xb, xb, 0, 1);                        \
    f32x2 x67 = __builtin_shufflevector(xb, xb, 2, 3);                        \
    ai0 = PKFMA(x01, wih_i[0], ai0);  ai1 = PKFMA(x23, wih_i[1], ai1);        \
    af0 = PKFMA(x01, wih_f[0], af0);  af1 = PKFMA(x23, wih_f[1], af1);        \
    ag0 = PKFMA(x01, wih_g[0], ag0);  ag1 = PKFMA(x23, wih_g[1], ag1);        \
    ao0 = PKFMA(x01, wih_o[0], ao0);  ao1 = PKFMA(x23, wih_o[1], ao1);        \
    ai0 = PKFMA(x45, wih_i[2], ai0);  ai1 = PKFMA(x67, wih_i[3], ai1);        \
    af0 = PKFMA(x45, wih_f[2], af0);  af1 = PKFMA(x67, wih_f[3], af1);        \
    ag0 = PKFMA(x45, wih_g[2], ag0);  ag1 = PKFMA(x67, wih_g[3], ag1);        \
    ao0 = PKFMA(x45, wih_o[2], ao0);  ao1 = PKFMA(x67, wih_o[3], ao1);        \
    f32x2 si = ai0 + ai1;  float ui = si.x + si.y;                            \
    f32x2 sf = af0 + af1;  float uf = sf.x + sf.y;                            \
    f32x2 sg = ag0 + ag1;  float ug = sg.x + sg.y;                            \
    f32x2 so = ao0 + ao1;  float uo = so.x + so.y;                            \
    float iv  = RCP(1.0f + EXP2(ui));                                         \
    float fv  = RCP(1.0f + EXP2(uf));                                         \
    float rgv = RCP(1.0f + EXP2(ug));                                         \
    float ov  = RCP(1.0f + EXP2(uo));                                         \
    float g2  = fmaf(rgv, -2.0f * T2L, T2L);   /* g * T2L */                  \
    float n2o = -2.0f * ov;                                                   \
    c2 = fmaf(fv, c2, iv * g2);                /* c2 = c * T2L */             \
    float sc = RCP(1.0f + EXP2(c2));                                          \
    float h  = fmaf(sc, n2o, ov);              /* = o * tanh(c) */            \
    s_h[lane] = h;                             /* slots 30,31 garbage, unused */ \
    f32x4 hv0 = s_h4[chain*8+0], hv1 = s_h4[chain*8+1];                       \
    f32x4 hv2 = s_h4[chain*8+2], hv3 = s_h4[chain*8+3];                       \
    f32x4 hv4 = s_h4[chain*8+4], hv5 = s_h4[chain*8+5];                       \
    f32x4 hv6 = s_h4[chain*8+6], hv7 = s_h4[chain*8+7];                       \
    /* ---- read shadow ---- */                                               \
    float p = group32_reduce(h * wlin);                                       \
    if ((lane & 31) == 31) s_y[chain * SEQ + (T)] = p + blin;                 \
    /* ---- unpack (register aliasing of hv pairs) ---- */                    \
    hrf2[0]  = __builtin_shufflevector(hv0, hv0, 0, 1);                       \
    hrf2[1]  = __builtin_shufflevector(hv0, hv0, 2, 3);                       \
    hrf2[2]  = __builtin_shufflevector(hv1, hv1, 0, 1);                       \
    hrf2[3]  = __builtin_shufflevector(hv1, hv1, 2, 3);                       \
    hrf2[4]  = __builtin_shufflevector(hv2, hv2, 0, 1);                       \
    hrf2[5]  = __builtin_shufflevector(hv2, hv2, 2, 3);                       \
    hrf2[6]  = __builtin_shufflevector(hv3, hv3, 0, 1);                       \
    hrf2[7]  = __builtin_shufflevector(hv3, hv3, 2, 3);                       \
    hrf2[8]  = __builtin_shufflevector(hv4, hv4, 0, 1);                       \
    hrf2[9]  = __builtin_shufflevector(hv4, hv4, 2, 3);                       \
    hrf2[10] = __builtin_shufflevector(hv5, hv5, 0, 1);                       \
    hrf2[11] = __builtin_shufflevector(hv5, hv5, 2, 3);                       \
    hrf2[12] = __builtin_shufflevector(hv6, hv6, 0, 1);                       \
    hrf2[13] = __builtin_shufflevector(hv6, hv6, 2, 3);                       \
    hrf2[14] = __builtin_shufflevector(hv7, hv7, 0, 1);                       \
} while (0)

    for (int ch = 0; ch < SEQ / 64; ++ch) {
        STAGEWRITE(ch + 1);
        STAGELOAD(ch + 2);
        const int t0 = ch * 64;
#pragma unroll 2
        for (int tt = 0; tt < 64; ++tt) {
            STEP(t0 + tt);
        }
    }
#undef STEP
#undef STAGELOAD
#undef STAGEWRITE

    // ---- dump y for both chains ----
    __syncthreads();  // single wave; orders the last ds_write before reads
    const float4* s_y4 = reinterpret_cast<const float4*>(s_y);
#pragma unroll 2
    for (int c = 0; c < 2; ++c) {
#pragma unroll 4
        for (int it = 0; it < SEQ / 256; ++it) {
            int tbase = it * 256 + lane * 4;
            float4 v = s_y4[(c * SEQ + tbase) >> 2];
            out[(size_t)(tbase + 0) * BATCH + b0 + c] = v.x;
            out[(size_t)(tbase + 1) * BATCH + b0 + c] = v.y;
            out[(size_t)(tbase + 2) * BATCH + b0 + c] = v.z;
            out[(size_t)(tbase + 3) * BATCH + b0 + c] = v.w;
        }
    }
}

extern "C" void kernel_launch(void* const* d_in, const int* in_sizes, int n_in,
                              void* d_out, int out_size, void* d_ws, size_t ws_size,
                              hipStream_t stream) {
    const float* x     = (const float*)d_in[0];
    const float* W_ih  = (const float*)d_in[1];
    const float* W_hh  = (const float*)d_in[2];
    const float* b_ih  = (const float*)d_in[3];
    const float* b_hh  = (const float*)d_in[4];
    const float* W_lin = (const float*)d_in[5];
    const float* b_lin = (const float*)d_in[6];
    float* out = (float*)d_out;

    lstm_chain_kernel<<<dim3(BATCH / 2), dim3(64), 0, stream>>>(
        x, W_ih, W_hh, b_ih, b_hh, W_lin, b_lin, out);
}

// Round 18
// 963.086 us; speedup vs baseline: 1.7315x; 1.4384x over previous
//
#include <hip/hip_runtime.h>

#define SEQ 4096
#define BATCH 512
#define INP 8
#define HID 30
#define LOG2E 1.44269504088896340736f

typedef float f32x2 __attribute__((ext_vector_type(2)));
typedef float f32x4 __attribute__((ext_vector_type(4)));
typedef unsigned uint2v __attribute__((ext_vector_type(2)));

#define RCP(v)  __builtin_amdgcn_rcpf(v)
#if __has_builtin(__builtin_amdgcn_exp2f)
#define EXP2(v) __builtin_amdgcn_exp2f(v)
#else
#define EXP2(v) exp2f(v)
#endif
#define PKFMA(a, b, c) __builtin_elementwise_fma(a, b, c)

__device__ __forceinline__ f32x2 mk2(float a, float b) {
    f32x2 r; r.x = a; r.y = b; return r;
}

// permlane32_swap with both operands = v:
//   returns {lo_rep = [v_lo32 | v_lo32], hi_rep = [v_hi32 | v_hi32]}
__device__ __forceinline__ void rep_halves(float v, float& lo_rep, float& hi_rep) {
#if __has_builtin(__builtin_amdgcn_permlane32_swap)
    uint2v r = __builtin_amdgcn_permlane32_swap(
        __float_as_uint(v), __float_as_uint(v), false, false);
    lo_rep = __uint_as_float(r.x);
    hi_rep = __uint_as_float(r.y);
#else
    float other = __shfl_xor(v, 32, 64);
    bool hi = (threadIdx.x & 32) != 0;
    lo_rep = hi ? other : v;
    hi_rep = hi ? v : other;
#endif
}

template <int CTRL>
__device__ __forceinline__ float dpp_sum_step(float v) {
    return v + __uint_as_float(__builtin_amdgcn_update_dpp(
        0, (int)__float_as_uint(v), CTRL, 0xf, 0xf, true));
}

// Sum within each 32-lane group, pure VALU. Total valid in lanes 15,31,47,63.
__device__ __forceinline__ float group32_reduce(float v) {
    v = dpp_sum_step<0x111>(v);  // row_shr:1
    v = dpp_sum_step<0x112>(v);  // row_shr:2
    v = dpp_sum_step<0x114>(v);  // row_shr:4
    v = dpp_sum_step<0x118>(v);  // row_shr:8
#if __has_builtin(__builtin_amdgcn_permlane16_swap)
    uint2v r = __builtin_amdgcn_permlane16_swap(
        __float_as_uint(v), __float_as_uint(v), false, false);
    return __uint_as_float(r.x) + __uint_as_float(r.y);
#else
    return v + __shfl_xor(v, 16, 64);
#endif
}

// One wave per batch chain (512 waves). Recurrence loop is VMEM-free (x staged
// through double-buffered LDS chunks of 64 steps; the only vmcnt wait is on
// loads a full chunk old). h -> ds_write -> 8x ds_read_b128 issued
// immediately; DPP reduce / s_y / LOADXL / next-step ih-pre fill the read
// shadow. B-gate activation carries c2 = c*T2L as state and
// h = fma(sc, n2o, oo_u) keeps tail muls off the serial chain.
// This is the measured champion structure (R11, 945us): three multi-chain
// variants (stmt-interleave x2, SIMD lane-split) and four chain-surgery
// variants (readlane, 4-acc, dist-8 prefetch, shadow moves) all regressed.
__global__ __launch_bounds__(64)
__attribute__((amdgpu_waves_per_eu(1, 1)))
void lstm_chain_kernel(
    const float* __restrict__ x,     // [SEQ,BATCH,INP]
    const float* __restrict__ W_ih,  // [4H, INP]
    const float* __restrict__ W_hh,  // [4H, HID]
    const float* __restrict__ b_ih,  // [4H]
    const float* __restrict__ b_hh,  // [4H]
    const float* __restrict__ W_lin, // [1, HID]
    const float* __restrict__ b_lin, // [1]
    float* __restrict__ out)         // [SEQ,BATCH,1]
{
    const int lane = threadIdx.x;
    // XCD-aware swizzle: consecutive chains share 64B x-lines / 32B out
    // sectors on one XCD's L2.
    const int g    = blockIdx.x;
    const int b    = (g & 7) * (BATCH / 8) + (g >> 3);
    const int j    = lane & 31;
    const int half = lane >> 5;
    const int jc   = j < HID ? j : HID - 1;
    const int ra   = half * HID + jc;            // i (half0) / f (half1): sigmoid
    const int rb   = 2 * HID + half * HID + jc;  // g (half0, tanh) / o (half1, sigmoid)

    // exp2 folding: sigmoid(v)=rcp(1+2^(-log2e*v)); tanh(v)=1-2*rcp(1+2^(2*log2e*v))
    const float sA   = -LOG2E;
    const float sB   = half ? -LOG2E : 2.0f * LOG2E;
    const float T2L  = 2.0f * LOG2E;            // tanh(c) via exp2(c*T2L)
    const float IT2L = 1.0f / (2.0f * LOG2E);
    // B-gate output pre-scaled by T2L: Bv2 = Bv * T2L
    const float sclB2 = half ? T2L : -2.0f * T2L;
    const float addB2 = half ? 0.0f : T2L;

    // ---- packed per-lane weights, pre-scaled, pinned in VGPR pairs ----
    f32x2 wih2_a[INP / 2], wih2_b[INP / 2];
#pragma unroll
    for (int i = 0; i < INP / 2; ++i) {
        f32x2 wa = mk2(W_ih[ra * INP + 2 * i] * sA, W_ih[ra * INP + 2 * i + 1] * sA);
        f32x2 wb = mk2(W_ih[rb * INP + 2 * i] * sB, W_ih[rb * INP + 2 * i + 1] * sB);
        asm volatile("" : "+v"(wa));
        asm volatile("" : "+v"(wb));
        wih2_a[i] = wa;
        wih2_b[i] = wb;
    }
    f32x2 whh2_a[HID / 2], whh2_b[HID / 2];
#pragma unroll
    for (int k = 0; k < HID / 2; ++k) {
        f32x2 wa = mk2(W_hh[ra * HID + 2 * k] * sA, W_hh[ra * HID + 2 * k + 1] * sA);
        f32x2 wb = mk2(W_hh[rb * HID + 2 * k] * sB, W_hh[rb * HID + 2 * k + 1] * sB);
        asm volatile("" : "+v"(wa));
        asm volatile("" : "+v"(wb));
        whh2_a[k] = wa;
        whh2_b[k] = wb;
    }
    const float bias_sa = (b_ih[ra] + b_hh[ra]) * sA;
    const float bias_sb = (b_ih[rb] + b_hh[rb]) * sB;
    const float blin    = b_lin[0];
    const float wlin    = (j < HID) ? W_lin[j] : 0.0f;

    __shared__ float s_y[SEQ];
    __shared__ __align__(16) float s_h[64];           // 0..29 valid; 30..63 dup
    __shared__ __align__(16) float s_x[2 * 64 * INP]; // 2 chunk buffers

    f32x4* sx4 = reinterpret_cast<f32x4*>(s_x);
    const f32x4* sx4c = reinterpret_cast<const f32x4*>(s_x);

    f32x2 hrf2[HID / 2];
#pragma unroll
    for (int k = 0; k < HID / 2; ++k) hrf2[k] = mk2(0.0f, 0.0f);
    float c2 = 0.0f;  // carried state: c * T2L

    // ---- chunked x staging (vmcnt waits amortized to once per 64 steps) ----
    f32x4 stg0, stg1;

#define STAGELOAD(CH2) do {                                                   \
    int _b0 = (CH2) * 64 + (lane >> 1);                                       \
    int _b1 = _b0 + 32;                                                       \
    if (_b0 > SEQ - 1) _b0 = SEQ - 1;                                         \
    if (_b1 > SEQ - 1) _b1 = SEQ - 1;                                         \
    const f32x4* _p0 = (const f32x4*)(x + ((size_t)_b0 * BATCH + b) * INP) + (lane & 1); \
    const f32x4* _p1 = (const f32x4*)(x + ((size_t)_b1 * BATCH + b) * INP) + (lane & 1); \
    stg0 = *_p0;                                                              \
    stg1 = *_p1;                                                              \
} while (0)

#define STAGEWRITE(CHW) do {                                                  \
    f32x4* _d = sx4 + ((CHW) & 1) * 128;                                      \
    _d[lane]      = stg0;                                                     \
    _d[64 + lane] = stg1;                                                     \
} while (0)

#define LOADXL(XA, XB, TL) do {                                               \
    int _e = (((TL) >> 6) & 1) * 128 + ((TL) & 63) * 2;                       \
    XA = sx4c[_e];                                                            \
    XB = sx4c[_e + 1];                                                        \
} while (0)

    // rolling pre-activation (bias + W_ih·x) for the NEXT step
    f32x2 preA0, preA1, preB0, preB1;

#define IHPRE(XA, XB) do {                                                    \
    f32x2 x01 = __builtin_shufflevector(XA, XA, 0, 1);                        \
    f32x2 x23 = __builtin_shufflevector(XA, XA, 2, 3);                        \
    f32x2 x45 = __builtin_shufflevector(XB, XB, 0, 1);                        \
    f32x2 x67 = __builtin_shufflevector(XB, XB, 2, 3);                        \
    preA0 = mk2(bias_sa, 0.0f);  preB0 = mk2(bias_sb, 0.0f);                  \
    preA1 = mk2(0.0f, 0.0f);     preB1 = mk2(0.0f, 0.0f);                     \
    preA0 = PKFMA(x01, wih2_a[0], preA0);  preB0 = PKFMA(x01, wih2_b[0], preB0); \
    preA1 = PKFMA(x23, wih2_a[1], preA1);  preB1 = PKFMA(x23, wih2_b[1], preB1); \
    preA0 = PKFMA(x45, wih2_a[2], preA0);  preB0 = PKFMA(x45, wih2_b[2], preB0); \
    preA1 = PKFMA(x67, wih2_a[3], preA1);  preB1 = PKFMA(x67, wih2_b[3], preB1); \
} while (0)

    // prologue
    STAGELOAD(0);
    STAGEWRITE(0);
    STAGELOAD(1);

    f32x4 xA0, xB0, xA1, xB1, xA2, xB2, xA3, xB3;
    LOADXL(xA0, xB0, 0);  LOADXL(xA1, xB1, 1);
    LOADXL(xA2, xB2, 2);  LOADXL(xA3, xB3, 3);
    IHPRE(xA0, xB0);  // pre for t=0

    const f32x4* s_h4 = reinterpret_cast<const f32x4*>(s_h);

// STEP(T, XAn/XBn: slot holding x[T+1] (feeds rolling pre),
//         XAl/XBl: slot to reload with x[TL=T+4])
#define STEP(T, XAn, XBn, XAl, XBl, TL) do {                                  \
    f32x2 A0 = preA0, A1 = preA1, B0 = preB0, B1 = preB1;                     \
    _Pragma("unroll")                                                         \
    for (int k = 0; k < HID / 2 - 1; k += 2) {                                \
        A0 = PKFMA(hrf2[k],   whh2_a[k],   A0);                               \
        B0 = PKFMA(hrf2[k],   whh2_b[k],   B0);                               \
        A1 = PKFMA(hrf2[k+1], whh2_a[k+1], A1);                               \
        B1 = PKFMA(hrf2[k+1], whh2_b[k+1], B1);                               \
    }                                                                         \
    A0 = PKFMA(hrf2[HID/2-1], whh2_a[HID/2-1], A0);                           \
    B0 = PKFMA(hrf2[HID/2-1], whh2_b[HID/2-1], B0);                           \
    f32x2 As = A0 + A1;  float ua = As.x + As.y;                              \
    f32x2 Bs = B0 + B1;  float ub = Bs.x + Bs.y;                              \
    float Av  = RCP(1.0f + EXP2(ua));                                         \
    float ii, ff;                                                             \
    rep_halves(Av, ii, ff);   /* issue A-swap early: overlaps B trans chain */\
    float sBv = RCP(1.0f + EXP2(ub));                                         \
    float Bv2 = fmaf(sBv, sclB2, addB2);   /* B-gate output scaled by T2L */  \
    float gg2, oT2;                                                           \
    rep_halves(Bv2, gg2, oT2);             /* gg2 = g*T2L, oT2 = o*T2L */     \
    float oo_u = oT2 * IT2L;               /* off-chain */                    \
    float n2o  = oT2 * (-2.0f * IT2L);     /* off-chain */                    \
    c2 = fmaf(ff, c2, ii * gg2);           /* c2 = c*T2L */                   \
    float sc = RCP(1.0f + EXP2(c2));                                          \
    float h  = fmaf(sc, n2o, oo_u);        /* = o * tanh(c) */                \
    s_h[lane] = h;                         /* ds_write */                     \
    f32x4 hv0 = s_h4[0], hv1 = s_h4[1], hv2 = s_h4[2], hv3 = s_h4[3];         \
    f32x4 hv4 = s_h4[4], hv5 = s_h4[5], hv6 = s_h4[6], hv7 = s_h4[7];         \
    /* ---- read shadow: independent work ---- */                             \
    float p = group32_reduce(h * wlin);                                       \
    if (lane == 31) s_y[T] = p + blin;                                        \
    LOADXL(XAl, XBl, TL);                                                     \
    IHPRE(XAn, XBn);                                                          \
    /* ---- unpack broadcast for next step ---- */                            \
    hrf2[0]  = __builtin_shufflevector(hv0, hv0, 0, 1);                       \
    hrf2[1]  = __builtin_shufflevector(hv0, hv0, 2, 3);                       \
    hrf2[2]  = __builtin_shufflevector(hv1, hv1, 0, 1);                       \
    hrf2[3]  = __builtin_shufflevector(hv1, hv1, 2, 3);                       \
    hrf2[4]  = __builtin_shufflevector(hv2, hv2, 0, 1);                       \
    hrf2[5]  = __builtin_shufflevector(hv2, hv2, 2, 3);                       \
    hrf2[6]  = __builtin_shufflevector(hv3, hv3, 0, 1);                       \
    hrf2[7]  = __builtin_shufflevector(hv3, hv3, 2, 3);                       \
    hrf2[8]  = __builtin_shufflevector(hv4, hv4, 0, 1);                       \
    hrf2[9]  = __builtin_shufflevector(hv4, hv4, 2, 3);                       \
    hrf2[10] = __builtin_shufflevector(hv5, hv5, 0, 1);                       \
    hrf2[11] = __builtin_shufflevector(hv5, hv5, 2, 3);                       \
    hrf2[12] = __builtin_shufflevector(hv6, hv6, 0, 1);                       \
    hrf2[13] = __builtin_shufflevector(hv6, hv6, 2, 3);                       \
    hrf2[14] = __builtin_shufflevector(hv7, hv7, 0, 1);                       \
} while (0)

    for (int ch = 0; ch < SEQ / 64; ++ch) {
        STAGEWRITE(ch + 1);
        STAGELOAD(ch + 2);
        const int t0 = ch * 64;
#pragma unroll 1
        for (int tt = 0; tt < 64; tt += 4) {
            const int t = t0 + tt;
            STEP(t + 0, xA1, xB1, xA0, xB0, t + 4);
            STEP(t + 1, xA2, xB2, xA1, xB1, t + 5);
            STEP(t + 2, xA3, xB3, xA2, xB2, t + 6);
            STEP(t + 3, xA0, xB0, xA3, xB3, t + 7);
        }
    }
#undef STEP
#undef IHPRE
#undef LOADXL
#undef STAGELOAD
#undef STAGEWRITE

    // ---- dump y: 4096 floats, 16 iterations of (ds_read_b128 + 4 stores) ----
    __syncthreads();  // single wave; orders the last ds_write before reads
    const float4* s_y4 = reinterpret_cast<const float4*>(s_y);
#pragma unroll 4
    for (int it = 0; it < SEQ / 256; ++it) {
        int tbase = it * 256 + lane * 4;
        float4 v = s_y4[tbase >> 2];
        out[(size_t)(tbase + 0) * BATCH + b] = v.x;
        out[(size_t)(tbase + 1) * BATCH + b] = v.y;
        out[(size_t)(tbase + 2) * BATCH + b] = v.z;
        out[(size_t)(tbase + 3) * BATCH + b] = v.w;
    }
}

extern "C" void kernel_launch(void* const* d_in, const int* in_sizes, int n_in,
                              void* d_out, int out_size, void* d_ws, size_t ws_size,
                              hipStream_t stream) {
    const float* x     = (const float*)d_in[0];
    const float* W_ih  = (const float*)d_in[1];
    const float* W_hh  = (const float*)d_in[2];
    const float* b_ih  = (const float*)d_in[3];
    const float* b_hh  = (const float*)d_in[4];
    const float* W_lin = (const float*)d_in[5];
    const float* b_lin = (const float*)d_in[6];
    float* out = (float*)d_out;

    lstm_chain_kernel<<<dim3(BATCH), dim3(64), 0, stream>>>(
        x, W_ih, W_hh, b_ih, b_hh, W_lin, b_lin, out);
}